// Round 11
// baseline (298.685 us; speedup 1.0000x reference)
//
#include <hip/hip_runtime.h>
#include <hip/hip_bf16.h>

#define DIM 384
#define SEQ 3136   // 56*56
#define NBATCH 8

typedef __attribute__((ext_vector_type(8))) short short8;  // 8 x bf16 (4 VGPRs)
typedef __attribute__((ext_vector_type(4))) float fx4;
typedef __attribute__((ext_vector_type(4))) int i4;
typedef __hip_bfloat16 bf16;

#define MFMA(a,b,c) __builtin_amdgcn_mfma_f32_16x16x32_bf16(a,b,c,0,0,0)

// -------- fused: x[b][c][n] f32 -> kb[b][n][c] bf16 (z<8), weights->bf16 (z==8) --------
__global__ __launch_bounds__(256) void ktransw(const float* __restrict__ x,
                                               bf16* __restrict__ kb,
                                               const float* __restrict__ w1,
                                               const float* __restrict__ w2,
                                               bf16* __restrict__ w1b,
                                               bf16* __restrict__ w2b) {
  if (blockIdx.z == 8) {   // weight conversion slice: 294 blocks x 512 elems
    int id = blockIdx.y * 49 + blockIdx.x;
    int i0 = id * 512 + threadIdx.x;
    if (i0 < DIM * DIM) { w1b[i0] = __float2bfloat16(w1[i0]); w2b[i0] = __float2bfloat16(w2[i0]); }
    int i1 = i0 + 256;
    if (i1 < DIM * DIM) { w1b[i1] = __float2bfloat16(w1[i1]); w2b[i1] = __float2bfloat16(w2[i1]); }
    return;
  }
  __shared__ float t[64][65];
  int b = blockIdx.z;
  int n0 = blockIdx.x * 64, c0 = blockIdx.y * 64;
  int tid = threadIdx.x;
  {
    int nl = tid & 63, cl = tid >> 6;
    const float* xp = x + ((size_t)b * DIM + c0) * SEQ + n0;
    #pragma unroll
    for (int p = 0; p < 16; ++p) {
      int c = cl * 16 + p;
      t[c][nl] = xp[(size_t)c * SEQ + nl];
    }
  }
  __syncthreads();
  {
    // paired stores: each lane writes 2 consecutive c as one bfloat162 (4B)
    int cp = (tid & 31) * 2, nr = tid >> 5;   // 32 col-pairs x 8 row-groups
    bf16* kp = kb + ((size_t)b * SEQ + n0) * DIM + c0;
    #pragma unroll
    for (int p = 0; p < 8; ++p) {
      int n = nr * 8 + p;
      __hip_bfloat162 v;
      v.x = __float2bfloat16(t[cp][n]);
      v.y = __float2bfloat16(t[cp + 1][n]);
      *reinterpret_cast<__hip_bfloat162*>(&kp[(size_t)n * DIM + cp]) = v;
    }
  }
}

// -------- fused dual GEMM: out[r][c] = sum_k A[r][k] * Bt[c][k]  (K=384) --------
// z<8:  Q[b][n][d] = Kb[b][n][:] . w1b[d][:]   (b = z)
// z>=8: Vt[b][d][m] = w2b[d][:] . Kb[b][m][:]  (b = z-8)
// Inner body = R7 kgemm (two 192-wide K-steps, LDS 51,200 B -> 3 blocks/CU).
// s_setprio(1) around the MFMA cluster (T5; R10-proven).
__global__ __launch_bounds__(256, 3) void kgemm2(const bf16* __restrict__ Kb,
                                                 const bf16* __restrict__ w1b,
                                                 const bf16* __restrict__ w2b,
                                                 bf16* __restrict__ Qb,
                                                 bf16* __restrict__ Vt) {
  __shared__ __align__(16) bf16 At[64][200];
  __shared__ __align__(16) bf16 Bs[64][200];
  int z = blockIdx.z, id = blockIdx.x;
  const bf16 *A, *Bt;
  bf16* out;
  long long Abs, Bbs, Obs;
  int ldo, bx, by, b;
  if (z < 8) {
    b = z; A = Kb; Abs = (long long)SEQ * DIM; Bt = w1b; Bbs = 0;
    out = Qb; Obs = (long long)SEQ * DIM; ldo = DIM;
    bx = id % 49; by = id / 49;              // 49 x 6
  } else {
    b = z - 8; A = w2b; Abs = 0; Bt = Kb; Bbs = (long long)SEQ * DIM;
    out = Vt; Obs = (long long)DIM * SEQ; ldo = SEQ;
    bx = id % 6; by = id / 6;                // 6 x 49
  }
  int tid = threadIdx.x;
  const bf16* Ab = A + (size_t)b * Abs + (size_t)bx * 64 * DIM;
  const bf16* Bb = Bt + (size_t)b * Bbs + (size_t)by * 64 * DIM;
  int row = tid >> 2, cb = (tid & 3) * 48;
  int wave = tid >> 6, lane = tid & 63;
  int r = lane & 15, kq = lane >> 4;
  fx4 zero = {0.f, 0.f, 0.f, 0.f};
  fx4 acc[4];
  #pragma unroll
  for (int i = 0; i < 4; ++i) acc[i] = zero;
  #pragma unroll
  for (int kb2 = 0; kb2 < DIM; kb2 += 192) {
    if (kb2) __syncthreads();   // all waves done reading previous K-step tiles
    {
      const i4* ga = (const i4*)(Ab + (size_t)row * DIM + kb2 + cb);
      const i4* gb = (const i4*)(Bb + (size_t)row * DIM + kb2 + cb);
      i4* la = (i4*)(&At[row][cb]);
      i4* lb = (i4*)(&Bs[row][cb]);
      #pragma unroll
      for (int p = 0; p < 6; ++p) { la[p] = ga[p]; lb[p] = gb[p]; }
    }
    __syncthreads();
    __builtin_amdgcn_s_setprio(1);
    #pragma unroll
    for (int ks = 0; ks < 6; ++ks) {
      short8 af = *(const short8*)(&At[wave * 16 + r][ks * 32 + kq * 8]);
      #pragma unroll
      for (int ct = 0; ct < 4; ++ct) {
        short8 bfr = *(const short8*)(&Bs[ct * 16 + r][ks * 32 + kq * 8]);
        acc[ct] = MFMA(af, bfr, acc[ct]);
      }
    }
    __builtin_amdgcn_s_setprio(0);
  }
  bf16* ob = out + (size_t)b * Obs
           + (size_t)(bx * 64 + wave * 16 + kq * 4) * ldo + by * 64;
  #pragma unroll
  for (int ct = 0; ct < 4; ++ct)
    #pragma unroll
    for (int rr = 0; rr < 4; ++rr)
      ob[(size_t)rr * ldo + ct * 16 + r] = __float2bfloat16(acc[ct][rr]);
}

// -------- fused attention: S = Q*K^T (no-max softmax), O = P*V / rowsum --------
// R0 structure + setprio (R10-proven: 238 us). ONE change this round: the V
// fragment gathers are issued AFTER barrier A instead of before it. In R0 the
// compiler's vmcnt(0) drain at A force-completed them before QK began -- a
// serial L2-latency stall per iter. Post-A issue lets their latency drain at
// barrier B, fully covered by QK's 48 MFMAs + exp. vf liveness strictly
// SHRINKS (post-A -> PV); no register/layout/phase change. (Isolated retest of
// the one R6 component that was never separated from the gload_lds bundle.)
__global__ __launch_bounds__(256, 2) void kattn(const bf16* __restrict__ Qb,
                                                const bf16* __restrict__ Kb,
                                                const bf16* __restrict__ Vt,
                                                float* __restrict__ out) {
  __shared__ __align__(16) bf16 Kl[64][DIM + 8];   // 50176 B
  __shared__ __align__(16) bf16 Pl[4][16][68];     //  8704 B (stride 34 dw, odd/2)
  __shared__ float rsum[64];

  int b = blockIdx.x;
  int n0 = blockIdx.y * 64;
  int tid = threadIdx.x;
  int wave = tid >> 6, lane = tid & 63;
  int r = lane & 15, kq = lane >> 4;

  // Q fragments for this wave's 16 rows, full K=384 (12 k-steps)
  short8 qf[12];
  {
    const bf16* qp = Qb + ((size_t)b * SEQ + n0 + wave * 16 + r) * DIM + kq * 8;
    #pragma unroll
    for (int ks = 0; ks < 12; ++ks) qf[ks] = *(const short8*)(qp + ks * 32);
  }
  fx4 zero = {0.f, 0.f, 0.f, 0.f};
  fx4 acc[4][6];
  #pragma unroll
  for (int i = 0; i < 4; ++i)
    #pragma unroll
    for (int j = 0; j < 6; ++j) acc[i][j] = zero;
  float rs[4] = {0.f, 0.f, 0.f, 0.f};
  const float cexp = 0.07362223f;   // log2(e)/sqrt(384): exp(s*scale) = exp2(s*cexp)

  const bf16* kbase = Kb + (size_t)b * SEQ * DIM;
  const bf16* vbase = Vt + (size_t)b * DIM * SEQ;

  // staging geometry (per thread): one K row quarter
  int srow = tid >> 2, scb = (tid & 3) * 96;

  for (int im = 0; im < SEQ / 64; ++im) {
    int m0 = im * 64;
    { // stage K tile: 64 rows x 384 bf16 (reg-staged)
      const i4* g = (const i4*)(kbase + (size_t)(m0 + srow) * DIM + scb);
      i4* l = (i4*)(&Kl[srow][scb]);
      #pragma unroll
      for (int p = 0; p < 12; ++p) l[p] = g[p];
    }
    __syncthreads();   // A: Kl ready; also all waves done PV(im-1) -> Pl free
    // V fragments issued POST-A: latency drains at barrier B, covered by QK+exp
    short8 vf[2][6];
    #pragma unroll
    for (int ks2 = 0; ks2 < 2; ++ks2)
      #pragma unroll
      for (int dtl = 0; dtl < 6; ++dtl) {
        int d = (wave * 6 + dtl) * 16 + r;
        vf[ks2][dtl] = *(const short8*)(vbase + (size_t)d * SEQ + m0 + ks2 * 32 + kq * 8);
      }
    // S = Q * K^T : wave's 16 rows x 64 cols
    fx4 sa[4];
    #pragma unroll
    for (int ct = 0; ct < 4; ++ct) sa[ct] = zero;
    __builtin_amdgcn_s_setprio(1);
    #pragma unroll
    for (int ks = 0; ks < 12; ++ks) {
      #pragma unroll
      for (int ct = 0; ct < 4; ++ct) {
        short8 bfr = *(const short8*)(&Kl[ct * 16 + r][ks * 32 + kq * 8]);
        sa[ct] = MFMA(qf[ks], bfr, sa[ct]);
      }
    }
    __builtin_amdgcn_s_setprio(0);
    // exp (no max subtraction), partial rowsum (per-lane, reduce deferred), P -> LDS
    #pragma unroll
    for (int rr = 0; rr < 4; ++rr) {
      float e0 = exp2f(sa[0][rr] * cexp);
      float e1 = exp2f(sa[1][rr] * cexp);
      float e2 = exp2f(sa[2][rr] * cexp);
      float e3 = exp2f(sa[3][rr] * cexp);
      int row = kq * 4 + rr;
      Pl[wave][row][r]      = __float2bfloat16(e0);
      Pl[wave][row][16 + r] = __float2bfloat16(e1);
      Pl[wave][row][32 + r] = __float2bfloat16(e2);
      Pl[wave][row][48 + r] = __float2bfloat16(e3);
      rs[rr] += (e0 + e1) + (e2 + e3);
    }
    __syncthreads();   // B: Pl ready (drains vf loads too); Kl free next iter
    // PV: O[rg*16+i][d] += P[rg*16+i][m] * V[m][d], wave's 96 d-cols
    __builtin_amdgcn_s_setprio(1);
    #pragma unroll
    for (int ks2 = 0; ks2 < 2; ++ks2) {
      short8 pa[4];
      #pragma unroll
      for (int rg = 0; rg < 4; ++rg)
        pa[rg] = *(const short8*)(&Pl[rg][r][ks2 * 32 + kq * 8]);
      #pragma unroll
      for (int dtl = 0; dtl < 6; ++dtl) {
        #pragma unroll
        for (int rg = 0; rg < 4; ++rg)
          acc[rg][dtl] = MFMA(pa[rg], vf[ks2][dtl], acc[rg][dtl]);
      }
    }
    __builtin_amdgcn_s_setprio(0);
  }
  // final rowsum reduce over the 16 r-lanes (cols partition), share across waves
  #pragma unroll
  for (int rr = 0; rr < 4; ++rr) {
    float v = rs[rr];
    v += __shfl_xor(v, 1);
    v += __shfl_xor(v, 2);
    v += __shfl_xor(v, 4);
    v += __shfl_xor(v, 8);
    if (r == 0) rsum[wave * 16 + kq * 4 + rr] = v;
  }
  __syncthreads();
  // epilogue: divide and store transposed: out[b][d][n]
  float* ob = out + (size_t)b * DIM * SEQ;
  #pragma unroll
  for (int rg = 0; rg < 4; ++rg) {
    #pragma unroll
    for (int rr = 0; rr < 4; ++rr) {
      float inv = 1.0f / rsum[rg * 16 + kq * 4 + rr];
      int n = n0 + rg * 16 + kq * 4 + rr;
      #pragma unroll
      for (int dtl = 0; dtl < 6; ++dtl) {
        int d = (wave * 6 + dtl) * 16 + r;
        ob[(size_t)d * SEQ + n] = acc[rg][dtl][rr] * inv;
      }
    }
  }
}

extern "C" void kernel_launch(void* const* d_in, const int* in_sizes, int n_in,
                              void* d_out, int out_size, void* d_ws, size_t ws_size,
                              hipStream_t stream) {
  const float* x  = (const float*)d_in[0];
  const float* w1 = (const float*)d_in[1];
  const float* w2 = (const float*)d_in[2];
  float* out = (float*)d_out;

  char* ws = (char*)d_ws;
  size_t SZ = (size_t)NBATCH * SEQ * DIM * sizeof(bf16);   // 19,267,584 B
  bf16* Kb  = (bf16*)(ws);                 // [B][N][C]
  bf16* Qb  = (bf16*)(ws + SZ);            // [B][N][C]
  bf16* Vt  = (bf16*)(ws + 2 * SZ);        // [B][C][N]
  bf16* w1b = (bf16*)(ws + 3 * SZ);
  bf16* w2b = (bf16*)(ws + 3 * SZ + (size_t)DIM * DIM * sizeof(bf16));

  // 1) transpose+convert x -> Kb; weights -> bf16 (fused, z==8 slice)
  ktransw<<<dim3(SEQ / 64, DIM / 64, NBATCH + 1), 256, 0, stream>>>(
      x, Kb, w1, w2, w1b, w2b);
  // 2) fused dual GEMM: z<8 -> Qb, z>=8 -> Vt
  kgemm2<<<dim3(294, 1, 2 * NBATCH), 256, 0, stream>>>(Kb, w1b, w2b, Qb, Vt);
  // 3) fused attention -> out[b][d][n]  (batch on blockIdx.x -> one XCD per batch)
  kattn<<<dim3(NBATCH, SEQ / 64), 256, 0, stream>>>(Qb, Kb, Vt, out);
}

// Round 12
// 266.300 us; speedup vs baseline: 1.1216x; 1.1216x over previous
//
#include <hip/hip_runtime.h>
#include <hip/hip_bf16.h>

#define DIM 384
#define SEQ 3136   // 56*56
#define NBATCH 8

typedef __attribute__((ext_vector_type(8))) short short8;  // 8 x bf16 (4 VGPRs)
typedef __attribute__((ext_vector_type(4))) float fx4;
typedef __attribute__((ext_vector_type(4))) int i4;
typedef __hip_bfloat16 bf16;

#define MFMA(a,b,c) __builtin_amdgcn_mfma_f32_16x16x32_bf16(a,b,c,0,0,0)

// -------- fused: x[b][c][n] f32 -> kb[b][n][c] bf16 (z<8), weights->bf16 (z==8) --------
__global__ __launch_bounds__(256) void ktransw(const float* __restrict__ x,
                                               bf16* __restrict__ kb,
                                               const float* __restrict__ w1,
                                               const float* __restrict__ w2,
                                               bf16* __restrict__ w1b,
                                               bf16* __restrict__ w2b) {
  if (blockIdx.z == 8) {   // weight conversion slice: 294 blocks x 512 elems
    int id = blockIdx.y * 49 + blockIdx.x;
    int i0 = id * 512 + threadIdx.x;
    if (i0 < DIM * DIM) { w1b[i0] = __float2bfloat16(w1[i0]); w2b[i0] = __float2bfloat16(w2[i0]); }
    int i1 = i0 + 256;
    if (i1 < DIM * DIM) { w1b[i1] = __float2bfloat16(w1[i1]); w2b[i1] = __float2bfloat16(w2[i1]); }
    return;
  }
  __shared__ float t[64][65];
  int b = blockIdx.z;
  int n0 = blockIdx.x * 64, c0 = blockIdx.y * 64;
  int tid = threadIdx.x;
  {
    int nl = tid & 63, cl = tid >> 6;
    const float* xp = x + ((size_t)b * DIM + c0) * SEQ + n0;
    #pragma unroll
    for (int p = 0; p < 16; ++p) {
      int c = cl * 16 + p;
      t[c][nl] = xp[(size_t)c * SEQ + nl];
    }
  }
  __syncthreads();
  {
    // paired stores: each lane writes 2 consecutive c as one bfloat162 (4B)
    int cp = (tid & 31) * 2, nr = tid >> 5;   // 32 col-pairs x 8 row-groups
    bf16* kp = kb + ((size_t)b * SEQ + n0) * DIM + c0;
    #pragma unroll
    for (int p = 0; p < 8; ++p) {
      int n = nr * 8 + p;
      __hip_bfloat162 v;
      v.x = __float2bfloat16(t[cp][n]);
      v.y = __float2bfloat16(t[cp + 1][n]);
      *reinterpret_cast<__hip_bfloat162*>(&kp[(size_t)n * DIM + cp]) = v;
    }
  }
}

// -------- fused dual GEMM: out[r][c] = sum_k A[r][k] * Bt[c][k]  (K=384) --------
// z<8:  Q[b][n][d] = Kb[b][n][:] . w1b[d][:]   (b = z)
// z>=8: Vt[b][d][m] = w2b[d][:] . Kb[b][m][:]  (b = z-8)
// Inner body = R7 kgemm (two 192-wide K-steps, LDS 51,200 B -> 3 blocks/CU).
// s_setprio(1) around the MFMA cluster (T5; R10-proven).
__global__ __launch_bounds__(256, 3) void kgemm2(const bf16* __restrict__ Kb,
                                                 const bf16* __restrict__ w1b,
                                                 const bf16* __restrict__ w2b,
                                                 bf16* __restrict__ Qb,
                                                 bf16* __restrict__ Vt) {
  __shared__ __align__(16) bf16 At[64][200];
  __shared__ __align__(16) bf16 Bs[64][200];
  int z = blockIdx.z, id = blockIdx.x;
  const bf16 *A, *Bt;
  bf16* out;
  long long Abs, Bbs, Obs;
  int ldo, bx, by, b;
  if (z < 8) {
    b = z; A = Kb; Abs = (long long)SEQ * DIM; Bt = w1b; Bbs = 0;
    out = Qb; Obs = (long long)SEQ * DIM; ldo = DIM;
    bx = id % 49; by = id / 49;              // 49 x 6
  } else {
    b = z - 8; A = w2b; Abs = 0; Bt = Kb; Bbs = (long long)SEQ * DIM;
    out = Vt; Obs = (long long)DIM * SEQ; ldo = SEQ;
    bx = id % 6; by = id / 6;                // 6 x 49
  }
  int tid = threadIdx.x;
  const bf16* Ab = A + (size_t)b * Abs + (size_t)bx * 64 * DIM;
  const bf16* Bb = Bt + (size_t)b * Bbs + (size_t)by * 64 * DIM;
  int row = tid >> 2, cb = (tid & 3) * 48;
  int wave = tid >> 6, lane = tid & 63;
  int r = lane & 15, kq = lane >> 4;
  fx4 zero = {0.f, 0.f, 0.f, 0.f};
  fx4 acc[4];
  #pragma unroll
  for (int i = 0; i < 4; ++i) acc[i] = zero;
  #pragma unroll
  for (int kb2 = 0; kb2 < DIM; kb2 += 192) {
    if (kb2) __syncthreads();   // all waves done reading previous K-step tiles
    {
      const i4* ga = (const i4*)(Ab + (size_t)row * DIM + kb2 + cb);
      const i4* gb = (const i4*)(Bb + (size_t)row * DIM + kb2 + cb);
      i4* la = (i4*)(&At[row][cb]);
      i4* lb = (i4*)(&Bs[row][cb]);
      #pragma unroll
      for (int p = 0; p < 6; ++p) { la[p] = ga[p]; lb[p] = gb[p]; }
    }
    __syncthreads();
    __builtin_amdgcn_s_setprio(1);
    #pragma unroll
    for (int ks = 0; ks < 6; ++ks) {
      short8 af = *(const short8*)(&At[wave * 16 + r][ks * 32 + kq * 8]);
      #pragma unroll
      for (int ct = 0; ct < 4; ++ct) {
        short8 bfr = *(const short8*)(&Bs[ct * 16 + r][ks * 32 + kq * 8]);
        acc[ct] = MFMA(af, bfr, acc[ct]);
      }
    }
    __builtin_amdgcn_s_setprio(0);
  }
  bf16* ob = out + (size_t)b * Obs
           + (size_t)(bx * 64 + wave * 16 + kq * 4) * ldo + by * 64;
  #pragma unroll
  for (int ct = 0; ct < 4; ++ct)
    #pragma unroll
    for (int rr = 0; rr < 4; ++rr)
      ob[(size_t)rr * ldo + ct * 16 + r] = __float2bfloat16(acc[ct][rr]);
}

// -------- fused attention: S = Q*K^T (no-max softmax), O = P*V / rowsum --------
// R0 structure + setprio (R10-proven best: kattn 238 us). V gathers MUST stay
// at loop top, BEFORE barrier A: they fly concurrently with the K-staging
// globals and drain together at A as ONE overlapped latency exposure. R11
// measured the post-A variant at +31 us (two serialized exposures; V issue
// delayed behind QK ds_reads). Ten perturbations of this structure tested:
// only setprio helped. 128 VGPR + ~128 AGPR at 2 blocks/CU is exactly
// saturated -- do not modify phase structure, placement, or liveness.
__global__ __launch_bounds__(256, 2) void kattn(const bf16* __restrict__ Qb,
                                                const bf16* __restrict__ Kb,
                                                const bf16* __restrict__ Vt,
                                                float* __restrict__ out) {
  __shared__ __align__(16) bf16 Kl[64][DIM + 8];   // 50176 B
  __shared__ __align__(16) bf16 Pl[4][16][68];     //  8704 B (stride 34 dw, odd/2)
  __shared__ float rsum[64];

  int b = blockIdx.x;
  int n0 = blockIdx.y * 64;
  int tid = threadIdx.x;
  int wave = tid >> 6, lane = tid & 63;
  int r = lane & 15, kq = lane >> 4;

  // Q fragments for this wave's 16 rows, full K=384 (12 k-steps)
  short8 qf[12];
  {
    const bf16* qp = Qb + ((size_t)b * SEQ + n0 + wave * 16 + r) * DIM + kq * 8;
    #pragma unroll
    for (int ks = 0; ks < 12; ++ks) qf[ks] = *(const short8*)(qp + ks * 32);
  }
  fx4 zero = {0.f, 0.f, 0.f, 0.f};
  fx4 acc[4][6];
  #pragma unroll
  for (int i = 0; i < 4; ++i)
    #pragma unroll
    for (int j = 0; j < 6; ++j) acc[i][j] = zero;
  float rs[4] = {0.f, 0.f, 0.f, 0.f};
  const float cexp = 0.07362223f;   // log2(e)/sqrt(384): exp(s*scale) = exp2(s*cexp)

  const bf16* kbase = Kb + (size_t)b * SEQ * DIM;
  const bf16* vbase = Vt + (size_t)b * DIM * SEQ;

  // staging geometry (per thread): one K row quarter
  int srow = tid >> 2, scb = (tid & 3) * 96;

  for (int im = 0; im < SEQ / 64; ++im) {
    int m0 = im * 64;
    { // stage K tile: 64 rows x 384 bf16 (reg-staged)
      const i4* g = (const i4*)(kbase + (size_t)(m0 + srow) * DIM + scb);
      i4* l = (i4*)(&Kl[srow][scb]);
      #pragma unroll
      for (int p = 0; p < 12; ++p) l[p] = g[p];
    }
    // V fragments direct from global (L2): in flight WITH K staging (MLP)
    short8 vf[2][6];
    #pragma unroll
    for (int ks2 = 0; ks2 < 2; ++ks2)
      #pragma unroll
      for (int dtl = 0; dtl < 6; ++dtl) {
        int d = (wave * 6 + dtl) * 16 + r;
        vf[ks2][dtl] = *(const short8*)(vbase + (size_t)d * SEQ + m0 + ks2 * 32 + kq * 8);
      }
    __syncthreads();   // A: Kl ready; also all waves done PV(im-1) -> Pl free
    // S = Q * K^T : wave's 16 rows x 64 cols
    fx4 sa[4];
    #pragma unroll
    for (int ct = 0; ct < 4; ++ct) sa[ct] = zero;
    __builtin_amdgcn_s_setprio(1);
    #pragma unroll
    for (int ks = 0; ks < 12; ++ks) {
      #pragma unroll
      for (int ct = 0; ct < 4; ++ct) {
        short8 bfr = *(const short8*)(&Kl[ct * 16 + r][ks * 32 + kq * 8]);
        sa[ct] = MFMA(qf[ks], bfr, sa[ct]);
      }
    }
    __builtin_amdgcn_s_setprio(0);
    // exp (no max subtraction), partial rowsum (per-lane, reduce deferred), P -> LDS
    #pragma unroll
    for (int rr = 0; rr < 4; ++rr) {
      float e0 = exp2f(sa[0][rr] * cexp);
      float e1 = exp2f(sa[1][rr] * cexp);
      float e2 = exp2f(sa[2][rr] * cexp);
      float e3 = exp2f(sa[3][rr] * cexp);
      int row = kq * 4 + rr;
      Pl[wave][row][r]      = __float2bfloat16(e0);
      Pl[wave][row][16 + r] = __float2bfloat16(e1);
      Pl[wave][row][32 + r] = __float2bfloat16(e2);
      Pl[wave][row][48 + r] = __float2bfloat16(e3);
      rs[rr] += (e0 + e1) + (e2 + e3);
    }
    __syncthreads();   // B: Pl ready; also all waves done QK -> Kl free next iter
    // PV: O[rg*16+i][d] += P[rg*16+i][m] * V[m][d], wave's 96 d-cols
    __builtin_amdgcn_s_setprio(1);
    #pragma unroll
    for (int ks2 = 0; ks2 < 2; ++ks2) {
      short8 pa[4];
      #pragma unroll
      for (int rg = 0; rg < 4; ++rg)
        pa[rg] = *(const short8*)(&Pl[rg][r][ks2 * 32 + kq * 8]);
      #pragma unroll
      for (int dtl = 0; dtl < 6; ++dtl) {
        #pragma unroll
        for (int rg = 0; rg < 4; ++rg)
          acc[rg][dtl] = MFMA(pa[rg], vf[ks2][dtl], acc[rg][dtl]);
      }
    }
    __builtin_amdgcn_s_setprio(0);
  }
  // final rowsum reduce over the 16 r-lanes (cols partition), share across waves
  #pragma unroll
  for (int rr = 0; rr < 4; ++rr) {
    float v = rs[rr];
    v += __shfl_xor(v, 1);
    v += __shfl_xor(v, 2);
    v += __shfl_xor(v, 4);
    v += __shfl_xor(v, 8);
    if (r == 0) rsum[wave * 16 + kq * 4 + rr] = v;
  }
  __syncthreads();
  // epilogue: divide and store transposed: out[b][d][n]
  float* ob = out + (size_t)b * DIM * SEQ;
  #pragma unroll
  for (int rg = 0; rg < 4; ++rg) {
    #pragma unroll
    for (int rr = 0; rr < 4; ++rr) {
      float inv = 1.0f / rsum[rg * 16 + kq * 4 + rr];
      int n = n0 + rg * 16 + kq * 4 + rr;
      #pragma unroll
      for (int dtl = 0; dtl < 6; ++dtl) {
        int d = (wave * 6 + dtl) * 16 + r;
        ob[(size_t)d * SEQ + n] = acc[rg][dtl][rr] * inv;
      }
    }
  }
}

extern "C" void kernel_launch(void* const* d_in, const int* in_sizes, int n_in,
                              void* d_out, int out_size, void* d_ws, size_t ws_size,
                              hipStream_t stream) {
  const float* x  = (const float*)d_in[0];
  const float* w1 = (const float*)d_in[1];
  const float* w2 = (const float*)d_in[2];
  float* out = (float*)d_out;

  char* ws = (char*)d_ws;
  size_t SZ = (size_t)NBATCH * SEQ * DIM * sizeof(bf16);   // 19,267,584 B
  bf16* Kb  = (bf16*)(ws);                 // [B][N][C]
  bf16* Qb  = (bf16*)(ws + SZ);            // [B][N][C]
  bf16* Vt  = (bf16*)(ws + 2 * SZ);        // [B][C][N]
  bf16* w1b = (bf16*)(ws + 3 * SZ);
  bf16* w2b = (bf16*)(ws + 3 * SZ + (size_t)DIM * DIM * sizeof(bf16));

  // 1) transpose+convert x -> Kb; weights -> bf16 (fused, z==8 slice)
  ktransw<<<dim3(SEQ / 64, DIM / 64, NBATCH + 1), 256, 0, stream>>>(
      x, Kb, w1, w2, w1b, w2b);
  // 2) fused dual GEMM: z<8 -> Qb, z>=8 -> Vt
  kgemm2<<<dim3(294, 1, 2 * NBATCH), 256, 0, stream>>>(Kb, w1b, w2b, Qb, Vt);
  // 3) fused attention -> out[b][d][n]  (batch on blockIdx.x -> one XCD per batch)
  kattn<<<dim3(NBATCH, SEQ / 64), 256, 0, stream>>>(Qb, Kb, Vt, out);
}